// Round 5
// baseline (332.347 us; speedup 1.0000x reference)
//
#include <hip/hip_runtime.h>
#include <hip/hip_fp16.h>
#include <math.h>

// Problem constants (from reference)
#define B_TRAJ 16384
#define T_STEPS 60
#define D_IN 36
#define L_DIM 10
#define C_NUM 20
#define S_STAT 9
#define OUT_DIM 8
#define TT 2
#define NTILE (T_STEPS / TT)   // 30
#define XTS 1824               // per-traj xproj stride in halves (60*30 data + 24 pad)
#define GSTRIDE 88             // floats per group scratch (88%32=24 -> group bases hit banks 0,24,16,8)

#define LOG2E 1.4426950408889634f

typedef float f32x2 __attribute__((ext_vector_type(2)));
__device__ __forceinline__ f32x2 pkfma(f32x2 a, f32x2 b, f32x2 c) {
    // llvm.fma.v2f32 -> v_pk_fma_f32 on gfx950 (full-rate packed f32)
    return __builtin_elementwise_fma(a, b, c);
}
__device__ __forceinline__ float rcp_fast(float x) { return __builtin_amdgcn_rcpf(x); }
__device__ __forceinline__ float exp2_fast(float x) { return __builtin_amdgcn_exp2f(x); }
__device__ __forceinline__ float sigm_fast(float x) {
    return rcp_fast(1.0f + exp2_fast(x * -LOG2E));
}
__device__ __forceinline__ float tanh_fast(float x) {
    const float t = fminf(fmaxf(x * (2.0f * LOG2E), -30.0f), 30.0f);
    return fmaf(-2.0f, rcp_fast(exp2_fast(t) + 1.0f), 1.0f);
}
#define WFENCE() __builtin_amdgcn_wave_barrier()

// v9: re-parallelized scan — 16 lanes per trajectory (4 trajs per 64-thread
// block = one wave). Lane q<10 owns gate columns u_q, r_q, n_q AND ODE col q,
// so u/r/n/yi/blend are lane-local; only three 10-float vector broadcasts per
// step (yi, r*yi, y_new) plus the 20-float z broadcast. Every DS instruction
// serves 4 trajectories (was 2) -> DS ops/traj halved; emit cols 2-per-lane
// over 16 lanes -> VALU/traj ~0.6x. LDS 16.2 KB/block -> 10 blocks/CU.
// All sync is intra-wave (in-order DS + wave_barrier compiler fences).
__global__ __launch_bounds__(64)
void dgm2_v9(
    const float* __restrict__ data,        // [B, T, D]
    const float* __restrict__ time_steps,  // [T]
    const float* __restrict__ static_data, // [B, S]
    const float* __restrict__ W_update,    // [46, 10]
    const float* __restrict__ b_update,
    const float* __restrict__ W_reset,     // [46, 10]
    const float* __restrict__ b_reset,
    const float* __restrict__ W_new,       // [46, 10]
    const float* __restrict__ b_new,
    const float* __restrict__ W_emit,      // [30, 20]
    const float* __restrict__ b_emit,
    const float* __restrict__ W_ode,       // [10, 10]
    const float* __restrict__ b_ode,
    const float* __restrict__ W_mlp,       // [609, 8]
    const float* __restrict__ b_mlp,
    float* __restrict__ out)               // [B, 8]
{
    __shared__ __align__(16) __half xprojH[4 * XTS];    // 14592 B
    __shared__ __align__(16) float wbuf[4 * GSTRIDE];   // 1408 B: per-group scratch
                                                         //  (phase1 staging overlays: [4][2][36] = 288 f)
    __shared__ float dts[T_STEPS];                      // 240 B  => ~16.2 KB -> 10 blocks/CU

    const int tid  = threadIdx.x;
    const int g    = tid >> 4;      // group = local traj
    const int q    = tid & 15;      // lane within group
    const int traj = blockIdx.x * 4 + g;
    __half* xpj = xprojH + g * XTS;

    if (tid < T_STEPS) dts[tid] = (tid == 0) ? 0.01f : time_steps[tid] - time_steps[tid - 1];
    WFENCE();   // single wave: DS in-order; compiler fence only

    // helpers for the 30-column gate space (cols 0-9 u, 10-19 r, 20-29 n)
    auto gate_ptr = [&](int c) -> const float* {
        return c < 10 ? W_update : (c < 20 ? W_reset : W_new);
    };
    auto gate_col = [&](int c) -> int { return c < 10 ? c : (c < 20 ? c - 10 : c - 20); };
    auto gate_bias = [&](int c) -> float {
        return c < 10 ? b_update[c] : (c < 20 ? b_reset[c - 10] : b_new[c - 20]);
    };

    // ================= Phase 1: xproj precompute =================
    // lane handles cols c0 = q (0..15) and c1 = 16+q (16..29, valid q<14)
    {
        const int  c0   = q;
        const bool has1 = (q < 14);
        const int  c1   = has1 ? 16 + q : 29;
        const float* W0 = gate_ptr(c0); const int cc0 = gate_col(c0);
        const float* W1 = gate_ptr(c1); const int cc1 = gate_col(c1);

        f32x2 wxp0[18], wxp1[18];   // x-part rows 10..45
#pragma unroll
        for (int j = 0; j < 18; ++j) {
            wxp0[j] = (f32x2){W0[(L_DIM + 2 * j) * L_DIM + cc0],
                              W0[(L_DIM + 2 * j + 1) * L_DIM + cc0]};
            const f32x2 v1 = (f32x2){W1[(L_DIM + 2 * j) * L_DIM + cc1],
                                     W1[(L_DIM + 2 * j + 1) * L_DIM + cc1]};
            wxp1[j] = has1 ? v1 : (f32x2){0.0f, 0.0f};
        }
        const float bcol0 = gate_bias(c0);
        const float bcol1 = has1 ? gate_bias(c1) : 0.0f;

        // staging: 72 float4 chunks = [4 traj][2 tt][9 f4]; all 64 lanes stage
        // chunk tid, lanes 0-7 also chunk 64+tid. Prefetch held in registers.
        float* stagef = wbuf;
        const float* tb0 = data + (size_t)(blockIdx.x * 4) * (T_STEPS * D_IN);
        const int a_tr = tid / 18, a_rm = tid % 18, a_tt = a_rm / 9, a_c = a_rm % 9;
        const int bch = 64 + tid;
        const int b_tr = bch / 18, b_rm = bch % 18, b_tt = b_rm / 9, b_c = b_rm % 9;
        const bool hb = (tid < 8);

        {
            const float4 v0 = *reinterpret_cast<const float4*>(
                tb0 + (size_t)a_tr * (T_STEPS * D_IN) + a_tt * D_IN + a_c * 4);
            *reinterpret_cast<float4*>(stagef + (a_tr * TT + a_tt) * 36 + a_c * 4) = v0;
            if (hb) {
                const float4 v1 = *reinterpret_cast<const float4*>(
                    tb0 + (size_t)b_tr * (T_STEPS * D_IN) + b_tt * D_IN + b_c * 4);
                *reinterpret_cast<float4*>(stagef + (b_tr * TT + b_tt) * 36 + b_c * 4) = v1;
            }
        }
        WFENCE();

        for (int tile = 0; tile < NTILE; ++tile) {
            float4 pf0 = {}, pf1 = {};
            const bool more = (tile + 1 < NTILE);
            if (more) {
                pf0 = *reinterpret_cast<const float4*>(
                    tb0 + (size_t)a_tr * (T_STEPS * D_IN) + ((tile + 1) * TT + a_tt) * D_IN + a_c * 4);
                if (hb)
                    pf1 = *reinterpret_cast<const float4*>(
                        tb0 + (size_t)b_tr * (T_STEPS * D_IN) + ((tile + 1) * TT + b_tt) * D_IN + b_c * 4);
            }
#pragma unroll
            for (int tt = 0; tt < TT; ++tt) {
                const float* xrow = stagef + (g * TT + tt) * 36;
                f32x2 acc0 = (f32x2){bcol0, 0.0f};
                f32x2 acc1 = (f32x2){bcol1, 0.0f};
#pragma unroll
                for (int c = 0; c < 9; ++c) {
                    const float4 x4 = *reinterpret_cast<const float4*>(xrow + c * 4);
                    const f32x2 xlo = (f32x2){x4.x, x4.y};
                    const f32x2 xhi = (f32x2){x4.z, x4.w};
                    acc0 = pkfma(xlo, wxp0[2 * c], acc0);
                    acc0 = pkfma(xhi, wxp0[2 * c + 1], acc0);
                    acc1 = pkfma(xlo, wxp1[2 * c], acc1);
                    acc1 = pkfma(xhi, wxp1[2 * c + 1], acc1);
                }
                const int row = (tile * TT + tt) * 30;
                xpj[row + q] = __float2half(acc0.x + acc0.y);
                if (has1) xpj[row + 16 + q] = __float2half(acc1.x + acc1.y);
            }
            WFENCE();   // all lanes done reading this tile before overwrite
            if (more) {
                *reinterpret_cast<float4*>(stagef + (a_tr * TT + a_tt) * 36 + a_c * 4) = pf0;
                if (hb)
                    *reinterpret_cast<float4*>(stagef + (b_tr * TT + b_tt) * 36 + b_c * 4) = pf1;
            }
            WFENCE();
        }
    }

    // ================= Phase 2: sequential scan =================
    const bool qg = (q < 10);   // gate-column lane
    f32x2 wode2[5], wu2[5], wr2[5], wn2[5];   // y-part cols (rows 0..9)
#pragma unroll
    for (int j = 0; j < 5; ++j) {
        if (qg) {
            wode2[j] = (f32x2){W_ode[(2 * j) * L_DIM + q], W_ode[(2 * j + 1) * L_DIM + q]};
            wu2[j]   = (f32x2){W_update[(2 * j) * L_DIM + q], W_update[(2 * j + 1) * L_DIM + q]};
            wr2[j]   = (f32x2){W_reset[(2 * j) * L_DIM + q], W_reset[(2 * j + 1) * L_DIM + q]};
            wn2[j]   = (f32x2){W_new[(2 * j) * L_DIM + q], W_new[(2 * j + 1) * L_DIM + q]};
        } else {
            wode2[j] = wu2[j] = wr2[j] = wn2[j] = (f32x2){0.0f, 0.0f};
        }
    }
    const float bode = qg ? b_ode[q] : 0.0f;

    // emit: lane handles cols e0 = q (0..15) and e1 = 16+q (q<4)
    const int  e0  = q;
    const bool he1 = (q < 4);
    const int  e1  = he1 ? 16 + q : 19;
    f32x2 wez0[10], wez1[10], wey0[5], wey1[5];
#pragma unroll
    for (int j = 0; j < 10; ++j) {
        wez0[j] = (f32x2){W_emit[(2 * j) * C_NUM + e0], W_emit[(2 * j + 1) * C_NUM + e0]};
        const f32x2 v1 = (f32x2){W_emit[(2 * j) * C_NUM + e1], W_emit[(2 * j + 1) * C_NUM + e1]};
        wez1[j] = he1 ? v1 : (f32x2){0.0f, 0.0f};
    }
#pragma unroll
    for (int j = 0; j < 5; ++j) {
        wey0[j] = (f32x2){W_emit[(C_NUM + 2 * j) * C_NUM + e0], W_emit[(C_NUM + 2 * j + 1) * C_NUM + e0]};
        const f32x2 v1 = (f32x2){W_emit[(C_NUM + 2 * j) * C_NUM + e1], W_emit[(C_NUM + 2 * j + 1) * C_NUM + e1]};
        wey1[j] = he1 ? v1 : (f32x2){0.0f, 0.0f};
    }
    const float be0 = b_emit[e0];
    const float be1 = he1 ? b_emit[e1] : 0.0f;

    // group scratch: YI[0..15], YR[16..31], Y[32..47], Z[48..67] (floats)
    float* grp = wbuf + g * GSTRIDE;
    float* gYI = grp;
    float* gYR = grp + 16;
    float* gY  = grp + 32;
    float* gZ  = grp + 48;

    auto ldvec = [&](const float* p, f32x2* d) {
        const float4 a = *reinterpret_cast<const float4*>(p);
        const float4 b = *reinterpret_cast<const float4*>(p + 4);
        const float2 c = *reinterpret_cast<const float2*>(p + 8);
        d[0] = (f32x2){a.x, a.y}; d[1] = (f32x2){a.z, a.w};
        d[2] = (f32x2){b.x, b.y}; d[3] = (f32x2){b.z, b.w};
        d[4] = (f32x2){c.x, c.y};
    };

    f32x2 y2[5];
#pragma unroll
    for (int k = 0; k < 5; ++k) y2[k] = (f32x2){0.0f, 0.0f};
    float yown = 0.0f;
    gZ[q] = 0.0f;                   // carried unnormalized z; 0 => p=0 at t=0
    if (he1) gZ[16 + q] = 0.0f;
    WFENCE();

    for (int t = 0; t < T_STEPS; ++t) {
        const float dt = dts[t];

        // ---- ODE (lane-local column): yi_q = y_q + tanh(b + y.Wode[:,q])*dt ----
        f32x2 g2 = (f32x2){bode, 0.0f};
#pragma unroll
        for (int k = 0; k < 5; ++k) g2 = pkfma(y2[k], wode2[k], g2);
        const float yis = fmaf(tanh_fast(g2.x + g2.y), dt, yown);
        gYI[q] = yis;               // q>=10 -> pad slots 10..15
        WFENCE();
        f32x2 yi2[5];
        ldvec(gYI, yi2);

        // ---- gates (lane-local u_q, r_q): pre-act = xproj(f16, bias folded) + yi-part ----
        const float xau = __half2float(xpj[t * 30 + q]);
        const float xar = __half2float(xpj[t * 30 + 10 + q]);
        const float xan = __half2float(xpj[t * 30 + 20 + q]);  // q>=10 reads pad, unused result
        f32x2 au2 = (f32x2){xau, 0.0f};
        f32x2 ar2 = (f32x2){xar, 0.0f};
#pragma unroll
        for (int k = 0; k < 5; ++k) {
            au2 = pkfma(yi2[k], wu2[k], au2);
            ar2 = pkfma(yi2[k], wr2[k], ar2);
        }
        const float u = sigm_fast(au2.x + au2.y);
        const float r = sigm_fast(ar2.x + ar2.y);
        gYR[q] = r * yis;           // publish yr_q = r_q * yi_q
        WFENCE();
        f32x2 yr2[5];
        ldvec(gYR, yr2);

        // ---- candidate + blend (all lane-local) ----
        f32x2 an2 = (f32x2){xan, 0.0f};
#pragma unroll
        for (int k = 0; k < 5; ++k) an2 = pkfma(yr2[k], wn2[k], an2);
        const float nv = an2.x + an2.y;
        const float yn = fmaf(u, yis - nv, nv);
        yown = yn;
        gY[q] = yn;
        xpj[t * 30 + q] = __float2half(yn);   // stash y_t (cols 0..9 real; 10..15 pad, consumed row)
        WFENCE();
        ldvec(gY, y2);

        // ---- emitter: logit_c = b_c + (z_prev . We_p[:,c])/sum(z) + y . We_y[:,c] ----
        f32x2 zz[10];
        {
            const float4 z0 = *reinterpret_cast<const float4*>(gZ);
            const float4 z1 = *reinterpret_cast<const float4*>(gZ + 4);
            const float4 z2 = *reinterpret_cast<const float4*>(gZ + 8);
            const float4 z3 = *reinterpret_cast<const float4*>(gZ + 12);
            const float4 z4 = *reinterpret_cast<const float4*>(gZ + 16);
            zz[0] = (f32x2){z0.x, z0.y}; zz[1] = (f32x2){z0.z, z0.w};
            zz[2] = (f32x2){z1.x, z1.y}; zz[3] = (f32x2){z1.z, z1.w};
            zz[4] = (f32x2){z2.x, z2.y}; zz[5] = (f32x2){z2.z, z2.w};
            zz[6] = (f32x2){z3.x, z3.y}; zz[7] = (f32x2){z3.z, z3.w};
            zz[8] = (f32x2){z4.x, z4.y}; zz[9] = (f32x2){z4.z, z4.w};
        }
        f32x2 zd0 = (f32x2){0.0f, 0.0f}, zd1 = (f32x2){0.0f, 0.0f};
        f32x2 zs2 = (f32x2){0.0f, 0.0f};
#pragma unroll
        for (int j = 0; j < 10; ++j) {
            zd0 = pkfma(zz[j], wez0[j], zd0);
            zd1 = pkfma(zz[j], wez1[j], zd1);
            zs2 = zs2 + zz[j];
        }
        const float zsum = zs2.x + zs2.y;
        const float pinv = (t == 0) ? 0.0f : rcp_fast(zsum);
        f32x2 ev0 = (f32x2){fmaf(zd0.x + zd0.y, pinv, be0), 0.0f};
        f32x2 ev1 = (f32x2){fmaf(zd1.x + zd1.y, pinv, be1), 0.0f};
#pragma unroll
        for (int k = 0; k < 5; ++k) {
            ev0 = pkfma(y2[k], wey0[k], ev0);
            ev1 = pkfma(y2[k], wey1[k], ev1);
        }
        const float zv0 = exp2_fast(fminf((ev0.x + ev0.y) * LOG2E, 86.0f));
        const float zv1 = exp2_fast(fminf((ev1.x + ev1.y) * LOG2E, 86.0f));
        gZ[q] = zv0;
        if (he1) gZ[16 + q] = zv1;
        // no trailing fence: next step's fences precede the gZ read.
    }

    // ================= Phase 3: deferred MLP head =================
    // 16 lanes per traj: col = q&7, t-parity = q>>3; 1-shuffle reduce.
    WFENCE();
    {
        const int col = q & 7, tg = q >> 3;
        f32x2 o2 = (f32x2){0.0f, 0.0f};
        for (int tb = 0; tb < 30; ++tb) {
            const int t = tb * 2 + tg;
            const __half2* yh = reinterpret_cast<const __half2*>(xpj + t * 30);
            const float* wrow = W_mlp + (size_t)t * L_DIM * OUT_DIM + col;
#pragma unroll
            for (int q4 = 0; q4 < 5; ++q4) {
                const float2 yv = __half22float2(yh[q4]);
                const f32x2 w2 = (f32x2){wrow[(2 * q4) * OUT_DIM], wrow[(2 * q4 + 1) * OUT_DIM]};
                o2 = pkfma((f32x2){yv.x, yv.y}, w2, o2);
            }
        }
        float o8 = o2.x + o2.y;
        o8 += __shfl_xor(o8, 8, 16);
        if (q < OUT_DIM) {
            const float* stp = static_data + (size_t)traj * S_STAT;
            const float* wms = W_mlp + (size_t)(T_STEPS * L_DIM) * OUT_DIM;
#pragma unroll
            for (int i = 0; i < S_STAT; ++i) o8 += stp[i] * wms[i * OUT_DIM + q];
            out[(size_t)traj * OUT_DIM + q] = o8 + b_mlp[q];
        }
    }
}

extern "C" void kernel_launch(void* const* d_in, const int* in_sizes, int n_in,
                              void* d_out, int out_size, void* d_ws, size_t ws_size,
                              hipStream_t stream) {
    const float* data        = (const float*)d_in[0];
    const float* time_steps  = (const float*)d_in[1];
    const float* static_data = (const float*)d_in[2];
    const float* W_update    = (const float*)d_in[3];
    const float* b_update    = (const float*)d_in[4];
    const float* W_reset     = (const float*)d_in[5];
    const float* b_reset     = (const float*)d_in[6];
    const float* W_new       = (const float*)d_in[7];
    const float* b_new       = (const float*)d_in[8];
    const float* W_emit      = (const float*)d_in[9];
    const float* b_emit      = (const float*)d_in[10];
    const float* W_ode       = (const float*)d_in[11];
    const float* b_ode       = (const float*)d_in[12];
    const float* W_mlp       = (const float*)d_in[13];
    const float* b_mlp       = (const float*)d_in[14];
    float* out = (float*)d_out;

    // 4 trajectories per 64-thread block (one wave) -> 4096 blocks
    dim3 grid(B_TRAJ / 4), block(64);
    hipLaunchKernelGGL(dgm2_v9, grid, block, 0, stream,
                       data, time_steps, static_data,
                       W_update, b_update, W_reset, b_reset, W_new, b_new,
                       W_emit, b_emit, W_ode, b_ode, W_mlp, b_mlp, out);
}